// Round 13
// baseline (309.361 us; speedup 1.0000x reference)
//
#include <hip/hip_runtime.h>
#include <stdint.h>

#define NPATHS 4096
#define LPATH  8
#define DIM    256
#define HID    256

typedef short  short4v __attribute__((ext_vector_type(4)));
typedef short  short8v __attribute__((ext_vector_type(8)));
typedef float  float4v __attribute__((ext_vector_type(4)));

__device__ __forceinline__ unsigned short f2bf(float f) {
    union { float f; uint32_t u; } v; v.f = f;
    uint32_t u = v.u;
    u += 0x7FFFu + ((u >> 16) & 1u);   // round-to-nearest-even
    return (unsigned short)(u >> 16);
}
__device__ __forceinline__ float bf2f(unsigned short s) {
    return __uint_as_float(((uint32_t)s) << 16);
}
__device__ __forceinline__ float fast_sigmoid(float x) {
    return 1.0f / (1.0f + __expf(-x));
}
__device__ __forceinline__ float fast_tanh(float x) {
    x = fminf(15.0f, fmaxf(-15.0f, x));
    float e = __expf(2.0f * x);
    return (e - 1.0f) / (e + 1.0f);
}

// ---------------------------------------------------------------------------
// K0: pack weights into B-fragment order + bias + zero path_emb/done.
// WfB layout (shorts): [kc][quad][unit][gate][8]   (R13 relayout)
//   -> one lane's 4 gate fragments for a given kc are 64 B CONTIGUOUS:
//      mega loads them from ONE wave-uniform base (SGPR) + per-lane offset
//      with immediate offsets 0/16/32/48 (folds into the 13-bit imm).
//      Quarter-wave line coverage: load g=0 fetches each 64-B line, g=1..3
//      hit L1. Kills the per-iter per-gate 64-bit address VALU chains that
//      R12 counters showed (VALUBusy 31%, ~670 cyc/iter of addressing).
// Fragment CONTENTS per (g,kc,unit,quad,j) identical to the proven kernels:
//   element k = kc*32 + quad*8 + j of row g*256+unit.
// ---------------------------------------------------------------------------
__global__ void prep_kernel(const float* __restrict__ w_ih, const float* __restrict__ w_hh,
                            const float* __restrict__ b_ih, const float* __restrict__ b_hh,
                            unsigned short* __restrict__ WfB, float* __restrict__ bias,
                            float* __restrict__ path_emb, unsigned int* __restrict__ done) {
    int gid  = blockIdx.x * 256 + threadIdx.x;    // 0..131071
    int base = gid * 4;                           // short index, %4==0
    int j0   = base & 7;                          // 0 or 4
    int g    = (base >> 3) & 3;
    int unit = (base >> 5) & 255;
    int quad = (base >> 13) & 3;
    int kc   = base >> 15;                        // 0..15
    int row  = g * 256 + unit;
    int k    = kc * 32 + quad * 8 + j0;
    const float* src = (k < DIM) ? (w_ih + (size_t)row * DIM + k)
                                 : (w_hh + (size_t)row * HID + (k - DIM));
    float4 v = *(const float4*)src;
    short4v pk = {(short)f2bf(v.x), (short)f2bf(v.y), (short)f2bf(v.z), (short)f2bf(v.w)};
    *(short4v*)(WfB + base) = pk;
    if (gid < 1024) bias[gid] = b_ih[gid] + b_hh[gid];
    if (gid < 256)  path_emb[gid] = 0.0f;
    if (gid == 0)   *done = 0u;
}

// ---------------------------------------------------------------------------
// K1 (mega): ALL 8 LSTM steps in one kernel. 256 blocks x 1024 threads.
//
// SPILL LESSON (R3-R6): 1024-thread blocks get a ~64-VGPR budget; keep
// per-lane demand <= ~60. LDS LESSON (R8/R9): B staging through LDS is a
// pure pass-through -- stream B global->VGPR directly. LATENCY LESSON
// (R10-R12): consume-then-reload pipeline (acc=mfma(pa,pf); pf=load(next))
// gives each load a full iteration of lead at zero register cost.
//
// ADDRESSING LESSON (R12 -> R13): R12 measured 2140 cyc/iter vs the ~1024
// cyc/iter L1-miss-service floor, with VALUBusy 31% ~= 670 cyc/iter -- the
// kc loop recomputed four per-lane 64-bit gate addresses every iteration
// (gate stride 256 KB / kc stride 16 KB don't fit the 13-bit imm). R13's
// [kc][quad][unit][gate][8] layout makes the four loads ONE uniform base
// (bku = WfB + kcn*64KB, SALU) + ONE per-lane offset (loff, computed once)
// + imm offsets 0/16/32/48. In-loop address VALU ~= 0.
//
// Per-block kc ROTATION (kcn = half + ((i+blk&7)&7)) decorrelates the 32
// CUs/XCD that otherwise burst-request the same 64-KB slice each iteration.
// Accumulation order changes -> fp-rounding-level only.
//
// Block owns 16 paths x all 256 units -> recurrence block-local:
//   h: 8 KB XOR-swizzled LDS (bf16), c: registers (4 f32/lane),
//   x: gathered inline one step ahead (nontemporal). LDS total ~17 KB.
// At t=7: per-path max -> logits (block-owned), h -> h_final (de-swizzled).
// ---------------------------------------------------------------------------
__global__ __launch_bounds__(1024)
__attribute__((amdgpu_waves_per_eu(4, 4)))
void mega_kernel(const float* __restrict__ embedding, const int* __restrict__ paths,
                 const unsigned short* __restrict__ WfB, const float* __restrict__ bias,
                 unsigned short* __restrict__ h_final, float* __restrict__ logits) {
    __shared__ __align__(16) short sAx[8 * 512];      // x A-frags (8 KB)
    __shared__ __align__(16) short h_lds[16 * 256];   // h (bf16), XOR-swizzled (8 KB)
    __shared__ float red[16 * 16];                    // per-wave row-max partials

    const int tid  = threadIdx.x;
    const int w    = tid >> 6;        // 0..15
    const int lane = tid & 63;
    const int l15  = lane & 15;
    const int quad = lane >> 4;
    const int p0   = blockIdx.x * 16;
    const int unit = w * 16 + l15;    // this wave's unit-frag
    const int roff = blockIdx.x & 7;  // kc rotation (L2 decorrelation)

    const short* WfB_s = (const short*)WfB;
    const int loff = quad * 8192 + unit * 32;   // per-lane offset (shorts), fixed

    float bb[4];
#pragma unroll
    for (int g = 0; g < 4; ++g) bb[g] = bias[g * 256 + unit];

    // gather x(0): 4 floats/thread -> one b64 LDS write (fragment order)
    const int grow = tid & 15;            // path row
    const int gk0  = (tid >> 4) * 4;      // k offset 0..252
    const int gdst = (gk0 >> 5) * 512 + (((gk0 >> 3) & 3) * 16 + grow) * 8 + (gk0 & 4);
    {
        int node = paths[(p0 + grow) * LPATH];
        float4v v = __builtin_nontemporal_load(
            (const float4v*)(embedding + (size_t)node * DIM + gk0));
        short4v pk = {(short)f2bf(v[0]), (short)f2bf(v[1]),
                      (short)f2bf(v[2]), (short)f2bf(v[3])};
        *(short4v*)(&sAx[gdst]) = pk;
    }

    float cc[4] = {0.0f, 0.0f, 0.0f, 0.0f};

    __syncthreads();                      // x(0) staged

    // B prefetch prologue: first iteration of every step uses kc = roff
    short8v pf0, pf1, pf2, pf3;
    {
        const short* bk = WfB_s + ((size_t)roff << 15) + loff;
        pf0 = *(const short8v*)(bk);
        pf1 = *(const short8v*)(bk + 8);
        pf2 = *(const short8v*)(bk + 16);
        pf3 = *(const short8v*)(bk + 24);
    }

#pragma unroll 1
    for (int t = 0; t < LPATH; ++t) {
        const bool last = (t == LPATH - 1);
        const int  K    = (t == 0) ? 8 : 16;

        // issue gather of x(t+1) early (nontemporal; consumed at step tail)
        float4v gv;
        if (!last) {
            int node = paths[(p0 + grow) * LPATH + t + 1];
            gv = __builtin_nontemporal_load(
                (const float4v*)(embedding + (size_t)node * DIM + gk0));
        }

        float4v acc[4];
        const float4v z4 = {0.0f, 0.0f, 0.0f, 0.0f};
#pragma unroll
        for (int g = 0; g < 4; ++g) acc[g] = z4;

        // A prefetch for i=0 (kc = roff, x-half; sAx ready since last barrier)
        short8v pa = *(const short8v*)(sAx + roff * 512 + lane * 8);

        // kc loop: NO barriers; 1-iteration software pipeline on pa/pf.
#pragma unroll 1
        for (int i = 0; i < K; ++i) {
            int ip  = i + 1;
            // next kc in the flat schedule (next step starts at kc = roff;
            // dummy at the very end -- value overwritten at next step top)
            int kcn = (ip < K) ? ((ip < 8) ? ((ip + roff) & 7)
                                           : (8 + ((ip + roff) & 7)))
                               : roff;
            // uniform base (SALU) + fixed per-lane offset; g -> imm 0/16/32/48
            const short* bk = WfB_s + ((size_t)kcn << 15) + loff;

            // consume prefetched fragments; immediately re-issue same regs
            acc[0] = __builtin_amdgcn_mfma_f32_16x16x32_bf16(pa, pf0, acc[0], 0, 0, 0);
            pf0 = *(const short8v*)(bk);
            acc[1] = __builtin_amdgcn_mfma_f32_16x16x32_bf16(pa, pf1, acc[1], 0, 0, 0);
            pf1 = *(const short8v*)(bk + 8);
            acc[2] = __builtin_amdgcn_mfma_f32_16x16x32_bf16(pa, pf2, acc[2], 0, 0, 0);
            pf2 = *(const short8v*)(bk + 16);
            acc[3] = __builtin_amdgcn_mfma_f32_16x16x32_bf16(pa, pf3, acc[3], 0, 0, 0);
            pf3 = *(const short8v*)(bk + 24);

            // A for next iteration (LDS; within-step only -- the stale pa
            // loaded at the final iteration is discarded at the step top)
            if (kcn < 8) {
                pa = *(const short8v*)(sAx + kcn * 512 + lane * 8);
            } else {
                int cg  = (kcn - 8) * 4 + quad;   // 16-B group of h row
                int cgs = cg ^ (l15 & 7);         // XOR swizzle (bank-spread)
                pa = *(const short8v*)(&h_lds[l15 * 256 + cgs * 8]);
            }
        }

        // all waves' sAx/h_lds reads complete before the tail overwrites them
        __syncthreads();

        // stage sAx for next step
        if (!last) {
            short4v pk = {(short)f2bf(gv[0]), (short)f2bf(gv[1]),
                          (short)f2bf(gv[2]), (short)f2bf(gv[3])};
            *(short4v*)(&sAx[gdst]) = pk;
        }

        // pointwise LSTM update: 4 cells/lane, c persistent in registers
        float hv[4];
#pragma unroll
        for (int r = 0; r < 4; ++r) {
            float iv = acc[0][r] + bb[0];
            float fv = acc[1][r] + bb[1];
            float gg = acc[2][r] + bb[2];
            float ov = acc[3][r] + bb[3];
            float cn = fast_sigmoid(fv) * cc[r] + fast_sigmoid(iv) * fast_tanh(gg);
            cc[r] = cn;
            hv[r] = fast_sigmoid(ov) * fast_tanh(cn);
        }

        // write new h into h_lds (same XOR swizzle as the read side)
#pragma unroll
        for (int r = 0; r < 4; ++r) {
            int pr  = quad * 4 + r;
            int cgs = (unit >> 3) ^ (pr & 7);
            h_lds[pr * 256 + cgs * 8 + (unit & 7)] = (short)f2bf(hv[r]);
        }

        if (last) {
            // per-path max over this wave's 16 units -> LDS partials
#pragma unroll
            for (int r = 0; r < 4; ++r) {
                float m = hv[r];
                m = fmaxf(m, __shfl_xor(m, 1, 64));
                m = fmaxf(m, __shfl_xor(m, 2, 64));
                m = fmaxf(m, __shfl_xor(m, 4, 64));
                m = fmaxf(m, __shfl_xor(m, 8, 64));
                if (l15 == 0) red[(quad * 4 + r) * 16 + w] = m;
            }
        }
        __syncthreads();   // h_lds/sAx/red writes visible for next step reads
    }

    // logits: block-owned paths -> plain stores, no atomics
    if (tid < 16) {
        float m = red[tid * 16];
#pragma unroll
        for (int j = 1; j < 16; ++j) m = fmaxf(m, red[tid * 16 + j]);
        logits[p0 + tid] = m;
    }
    // h_final writeback, coalesced: de-swizzle (group i5 of row lives at
    // swizzled slot cgs = i5 ^ (row&7); store it at its TRUE offset i5*8).
    if (tid < 512) {
        int row = tid >> 5, i5 = tid & 31;
        int cgs = i5 ^ (row & 7);
        short8v v = *(const short8v*)(&h_lds[row * 256 + cgs * 8]);
        *(short8v*)(h_final + (size_t)(p0 + row) * HID + (size_t)i5 * 8) = v;
    }
}

// ---------------------------------------------------------------------------
// K2: fused softmax + attention + (last block) final linear+sigmoid.
// 256 blocks x 256 threads; each block redundantly computes the global
// softmax scalars from the 16 KB logits array, accumulates its 16 paths
// into path_emb, then the LAST block (device-scope ticket, properly
// fenced+barriered) computes out.
// ---------------------------------------------------------------------------
__global__ void attn_final_kernel(const unsigned short* __restrict__ h_final,
                                  const float* __restrict__ logits,
                                  float* __restrict__ path_emb,
                                  unsigned int* __restrict__ done,
                                  const float* __restrict__ embedding,
                                  const int* __restrict__ user_id,
                                  const int* __restrict__ item_id,
                                  const float* __restrict__ w_lin,
                                  const float* __restrict__ b_lin,
                                  float* __restrict__ out) {
    __shared__ float red[256];
    __shared__ float wts[16];
    __shared__ int lastf;
    int tid = threadIdx.x;
    int p0  = blockIdx.x * 16;

    float vals[16];
    float m = -1e30f;
#pragma unroll
    for (int i = 0; i < 16; ++i) {
        vals[i] = logits[i * 256 + tid];
        m = fmaxf(m, vals[i]);
    }
    red[tid] = m; __syncthreads();
    for (int s = 128; s > 0; s >>= 1) {
        if (tid < s) red[tid] = fmaxf(red[tid], red[tid + s]);
        __syncthreads();
    }
    m = red[0]; __syncthreads();
    float sum = 0.0f;
#pragma unroll
    for (int i = 0; i < 16; ++i) sum += __expf(vals[i] - m);
    red[tid] = sum; __syncthreads();
    for (int s = 128; s > 0; s >>= 1) {
        if (tid < s) red[tid] += red[tid + s];
        __syncthreads();
    }
    if (tid == 0) red[0] = 1.0f / red[0];
    __syncthreads();
    float invZ = red[0];
    if (tid < 16) wts[tid] = __expf(logits[p0 + tid] - m) * invZ;
    __syncthreads();

    float acc = 0.0f;
#pragma unroll
    for (int j = 0; j < 16; ++j)
        acc += wts[j] * bf2f(h_final[(size_t)(p0 + j) * HID + tid]);
    atomicAdd(&path_emb[tid], acc);

    // release: every thread's add made visible, then whole block synced,
    // THEN the ticket increments.
    __threadfence();
    __syncthreads();
    if (tid == 0) {
        unsigned int old = atomicAdd(done, 1u);
        lastf = (old == 255u) ? 1 : 0;
    }
    __syncthreads();
    if (lastf) {
        __threadfence();                 // acquire all blocks' partials
        float pe = __hip_atomic_load(&path_emb[tid], __ATOMIC_RELAXED,
                                     __HIP_MEMORY_SCOPE_AGENT);
        int u  = user_id[0];
        int it = item_id[0];
        float s = w_lin[tid]       * embedding[(size_t)u  * DIM + tid]
                + w_lin[256 + tid] * embedding[(size_t)it * DIM + tid]
                + w_lin[512 + tid] * pe;
        red[tid] = s; __syncthreads();
        for (int st = 128; st > 0; st >>= 1) {
            if (tid < st) red[tid] += red[tid + st];
            __syncthreads();
        }
        if (tid == 0) out[0] = 1.0f / (1.0f + __expf(-(red[0] + b_lin[0])));
    }
}

// ---------------------------------------------------------------------------
extern "C" void kernel_launch(void* const* d_in, const int* in_sizes, int n_in,
                              void* d_out, int out_size, void* d_ws, size_t ws_size,
                              hipStream_t stream) {
    const float* embedding = (const float*)d_in[0];
    const float* w_ih      = (const float*)d_in[1];
    const float* w_hh      = (const float*)d_in[2];
    const float* b_ih      = (const float*)d_in[3];
    const float* b_hh      = (const float*)d_in[4];
    const float* w_lin     = (const float*)d_in[5];
    const float* b_lin     = (const float*)d_in[6];
    const int*   paths     = (const int*)d_in[7];
    const int*   user_id   = (const int*)d_in[8];
    const int*   item_id   = (const int*)d_in[9];
    float* outp = (float*)d_out;

    // workspace layout (~3.1 MB), 256-B aligned
    char* ws = (char*)d_ws;
    size_t off = 0;
    auto alloc = [&](size_t n) { void* p = ws + off; off = (off + n + 255) & ~(size_t)255; return p; };
    unsigned short* WfB      = (unsigned short*)alloc((size_t)1024 * 512 * 2);   // 1 MB
    float*          bias     = (float*)alloc(1024 * 4);                          // 4 KB
    float*          path_emb = (float*)alloc(HID * 4);                           // 1 KB
    float*          logits   = (float*)alloc(NPATHS * 4);                        // 16 KB
    unsigned short* h_final  = (unsigned short*)alloc((size_t)NPATHS * HID * 2); // 2 MB
    unsigned int*   done     = (unsigned int*)alloc(4);

    prep_kernel<<<512, 256, 0, stream>>>(w_ih, w_hh, b_ih, b_hh, WfB, bias,
                                         path_emb, done);

    mega_kernel<<<256, 1024, 0, stream>>>(embedding, paths, WfB, bias,
                                          h_final, logits);

    attn_final_kernel<<<256, 256, 0, stream>>>(h_final, logits, path_emb, done,
                                               embedding, user_id, item_id,
                                               w_lin, b_lin, outp);
}